// Round 3
// baseline (58.338 us; speedup 1.0000x reference)
//
#include <hip/hip_runtime.h>

#define NUM_IDS 64
#define NB 65                 // bins 0..64 (0 = background)
#define HIST_BINS (NB * NB)   // 4225
#define G 256                 // blocks
#define T 256                 // threads/block

// Fused: per-block LDS histogram -> global atomic flush -> last block computes loss.
__global__ __launch_bounds__(T) void isl_fused_kernel(
    const int* __restrict__ pred, const int* __restrict__ tru,
    int* __restrict__ ghist, int* __restrict__ counter,
    float* __restrict__ out, int n4) {
    __shared__ int lh[HIST_BINS];
    __shared__ float ap[NUM_IDS], at[NUM_IDS];
    __shared__ float rowmax[NUM_IDS], colmax[NUM_IDS];
    __shared__ int is_last;

    const int tid = threadIdx.x;
    for (int i = tid; i < HIST_BINS; i += T) lh[i] = 0;
    __syncthreads();

    const int4* __restrict__ p4 = (const int4*)pred;
    const int4* __restrict__ t4 = (const int4*)tru;
    const int stride = G * T;
    int idx = blockIdx.x * T + tid;

    // Main: exactly n4/stride full rounds (4 for 1024x1024); hoist loads for MLP.
    int nfull = n4 / stride;
    int i = idx;
    while (nfull >= 4) {
        int4 pa = p4[i];            int4 ta = t4[i];
        int4 pb = p4[i + stride];   int4 tb = t4[i + stride];
        int4 pc = p4[i + 2*stride]; int4 tc = t4[i + 2*stride];
        int4 pd = p4[i + 3*stride]; int4 td = t4[i + 3*stride];
        atomicAdd(&lh[pa.x * NB + ta.x], 1);
        atomicAdd(&lh[pa.y * NB + ta.y], 1);
        atomicAdd(&lh[pa.z * NB + ta.z], 1);
        atomicAdd(&lh[pa.w * NB + ta.w], 1);
        atomicAdd(&lh[pb.x * NB + tb.x], 1);
        atomicAdd(&lh[pb.y * NB + tb.y], 1);
        atomicAdd(&lh[pb.z * NB + tb.z], 1);
        atomicAdd(&lh[pb.w * NB + tb.w], 1);
        atomicAdd(&lh[pc.x * NB + tc.x], 1);
        atomicAdd(&lh[pc.y * NB + tc.y], 1);
        atomicAdd(&lh[pc.z * NB + tc.z], 1);
        atomicAdd(&lh[pc.w * NB + tc.w], 1);
        atomicAdd(&lh[pd.x * NB + td.x], 1);
        atomicAdd(&lh[pd.y * NB + td.y], 1);
        atomicAdd(&lh[pd.z * NB + td.z], 1);
        atomicAdd(&lh[pd.w * NB + td.w], 1);
        i += 4 * stride;
        nfull -= 4;
    }
    for (; i < n4; i += stride) {   // remainder rounds + tail
        int4 p = p4[i];
        int4 t = t4[i];
        atomicAdd(&lh[p.x * NB + t.x], 1);
        atomicAdd(&lh[p.y * NB + t.y], 1);
        atomicAdd(&lh[p.z * NB + t.z], 1);
        atomicAdd(&lh[p.w * NB + t.w], 1);
    }
    __syncthreads();

    // Flush nonzero bins to global histogram.
    for (int b = tid; b < HIST_BINS; b += T) {
        int v = lh[b];
        if (v) atomicAdd(&ghist[b], v);
    }

    __threadfence();
    if (tid == 0) {
        int old = atomicAdd(counter, 1);
        is_last = (old == G - 1);
    }
    __syncthreads();
    if (!is_last) return;

    // Last block: coherent-point reads of the completed histogram.
    __threadfence();
    for (int b = tid; b < HIST_BINS; b += T) lh[b] = atomicAdd(&ghist[b], 0);
    __syncthreads();

    if (tid < NUM_IDS) {
        int s = 0;
        for (int j = 0; j < NB; ++j) s += lh[(tid + 1) * NB + j];
        ap[tid] = (float)s;
        int s2 = 0;
        for (int k = 0; k < NB; ++k) s2 += lh[k * NB + (tid + 1)];
        at[tid] = (float)s2;
    }
    __syncthreads();

    if (tid < NUM_IDS) {
        float a = ap[tid];
        float m = 0.f;
        for (int j = 0; j < NUM_IDS; ++j) {
            float inter = (float)lh[(tid + 1) * NB + (j + 1)];
            float uni = a + at[j] - inter;
            float iou = (uni > 0.f) ? inter / uni : 0.f;
            m = fmaxf(m, iou);
        }
        rowmax[tid] = m;

        float b = at[tid];
        float m2 = 0.f;
        for (int k = 0; k < NUM_IDS; ++k) {
            float inter = (float)lh[(k + 1) * NB + (tid + 1)];
            float uni = ap[k] + b - inter;
            float iou = (uni > 0.f) ? inter / uni : 0.f;
            m2 = fmaxf(m2, iou);
        }
        colmax[tid] = m2;
    }
    __syncthreads();

    if (tid == 0) {
        float loss = 0.f, cnt = 0.f;
        for (int k = 0; k < NUM_IDS; ++k) {
            if (ap[k] > 0.f) { loss += 1.f - rowmax[k]; cnt += 1.f; }
            if (at[k] > 0.f) { loss += 1.f - colmax[k]; cnt += 1.f; }
        }
        out[0] = (cnt > 0.f) ? loss / cnt : 0.f;
    }
}

extern "C" void kernel_launch(void* const* d_in, const int* in_sizes, int n_in,
                              void* d_out, int out_size, void* d_ws, size_t ws_size,
                              hipStream_t stream) {
    const int* pred = (const int*)d_in[0];
    const int* tru  = (const int*)d_in[1];
    float* out = (float*)d_out;
    int n = in_sizes[0];              // 1024*1024
    int* ghist = (int*)d_ws;          // 4225 ints
    int* counter = ghist + HIST_BINS; // 1 int

    hipMemsetAsync(ghist, 0, (HIST_BINS + 1) * sizeof(int), stream);
    isl_fused_kernel<<<G, T, 0, stream>>>(pred, tru, ghist, counter, out, n >> 2);
}

// Round 4
// 40.987 us; speedup vs baseline: 1.4233x; 1.4233x over previous
//
#include <hip/hip_runtime.h>

#define NUM_IDS 64
#define NB 65                 // bins 0..64 (0 = background)
#define HIST_BINS (NB * NB)   // 4225
#define T1 256                // hist threads/block
#define BINS_PER_BLK 64
#define G2 ((HIST_BINS + BINS_PER_BLK - 1) / BINS_PER_BLK)  // 67
#define T2 256

// Kernel A: per-block LDS histogram -> private partial slice (no atomics to gmem).
__global__ __launch_bounds__(T1) void isl_hist_kernel(
    const int* __restrict__ pred, const int* __restrict__ tru,
    int* __restrict__ part, int* __restrict__ counter, int n4, int g1) {
    __shared__ int lh[HIST_BINS];
    const int tid = threadIdx.x;
    if (blockIdx.x == 0 && tid == 0) *counter = 0;  // visible to kernel B at dispatch boundary
    for (int i = tid; i < HIST_BINS; i += T1) lh[i] = 0;
    __syncthreads();

    const int4* __restrict__ p4 = (const int4*)pred;
    const int4* __restrict__ t4 = (const int4*)tru;
    const int stride = g1 * T1;
#pragma unroll 2
    for (int i = blockIdx.x * T1 + tid; i < n4; i += stride) {
        int4 p = p4[i];
        int4 t = t4[i];
        atomicAdd(&lh[p.x * NB + t.x], 1);
        atomicAdd(&lh[p.y * NB + t.y], 1);
        atomicAdd(&lh[p.z * NB + t.z], 1);
        atomicAdd(&lh[p.w * NB + t.w], 1);
    }
    __syncthreads();

    int* dst = part + (size_t)blockIdx.x * HIST_BINS;
    for (int j = tid; j < HIST_BINS; j += T1) dst[j] = lh[j];
}

// Kernel B: parallel merge of partials -> C, last block computes the loss.
__global__ __launch_bounds__(T2) void isl_reduce_kernel(
    const int* __restrict__ part, int* __restrict__ C,
    int* __restrict__ counter, float* __restrict__ out, int g1) {
    __shared__ int acc[4][BINS_PER_BLK];
    __shared__ int lh[HIST_BINS];
    __shared__ float ap[NUM_IDS], at[NUM_IDS];
    __shared__ float rowmax[NUM_IDS], colmax[NUM_IDS];
    __shared__ int is_last;

    const int tid = threadIdx.x;
    const int lane = tid & 63;
    const int wave = tid >> 6;          // 0..3
    const int bin = blockIdx.x * BINS_PER_BLK + lane;

    int s = 0;
    if (bin < HIST_BINS) {
#pragma unroll 8
        for (int r = wave; r < g1; r += 4)          // coalesced: lanes -> consecutive bins
            s += part[(size_t)r * HIST_BINS + bin];
    }
    acc[wave][lane] = s;
    __syncthreads();

    if (wave == 0 && bin < HIST_BINS)
        C[bin] = acc[0][lane] + acc[1][lane] + acc[2][lane] + acc[3][lane];

    __threadfence();
    if (tid == 0) {
        int old = atomicAdd(counter, 1);
        is_last = (old == G2 - 1);
    }
    __syncthreads();
    if (!is_last) return;

    // Coherent-point reads of the completed histogram (cross-XCD safe).
    for (int b = tid; b < HIST_BINS; b += T2) lh[b] = atomicAdd(&C[b], 0);
    __syncthreads();

    if (tid < NUM_IDS) {
        int s1 = 0;
        for (int j = 0; j < NB; ++j) s1 += lh[(tid + 1) * NB + j];
        ap[tid] = (float)s1;
        int s2 = 0;
        for (int k = 0; k < NB; ++k) s2 += lh[k * NB + (tid + 1)];
        at[tid] = (float)s2;
    }
    __syncthreads();

    if (tid < NUM_IDS) {
        float a = ap[tid];
        float m = 0.f;
        for (int j = 0; j < NUM_IDS; ++j) {
            float inter = (float)lh[(tid + 1) * NB + (j + 1)];
            float uni = a + at[j] - inter;
            float iou = (uni > 0.f) ? inter / uni : 0.f;
            m = fmaxf(m, iou);
        }
        rowmax[tid] = m;

        float b = at[tid];
        float m2 = 0.f;
        for (int k = 0; k < NUM_IDS; ++k) {
            float inter = (float)lh[(k + 1) * NB + (tid + 1)];
            float uni = ap[k] + b - inter;
            float iou = (uni > 0.f) ? inter / uni : 0.f;
            m2 = fmaxf(m2, iou);
        }
        colmax[tid] = m2;
    }
    __syncthreads();

    if (tid == 0) {
        float loss = 0.f, cnt = 0.f;
        for (int k = 0; k < NUM_IDS; ++k) {
            if (ap[k] > 0.f) { loss += 1.f - rowmax[k]; cnt += 1.f; }
            if (at[k] > 0.f) { loss += 1.f - colmax[k]; cnt += 1.f; }
        }
        out[0] = (cnt > 0.f) ? loss / cnt : 0.f;
    }
}

extern "C" void kernel_launch(void* const* d_in, const int* in_sizes, int n_in,
                              void* d_out, int out_size, void* d_ws, size_t ws_size,
                              hipStream_t stream) {
    const int* pred = (const int*)d_in[0];
    const int* tru  = (const int*)d_in[1];
    float* out = (float*)d_out;
    int n = in_sizes[0];  // 1024*1024

    // Pick hist block count by available scratch: partials + C + counter.
    int g1 = 128;
    while (g1 > 32 &&
           ws_size < ((size_t)g1 * HIST_BINS + HIST_BINS + 16) * sizeof(int))
        g1 >>= 1;

    int* part = (int*)d_ws;                       // [g1][4225]
    int* C = part + (size_t)g1 * HIST_BINS;       // [4225]
    int* counter = C + HIST_BINS;                 // [1]

    isl_hist_kernel<<<g1, T1, 0, stream>>>(pred, tru, part, counter, n >> 2, g1);
    isl_reduce_kernel<<<G2, T2, 0, stream>>>(part, C, counter, out, g1);
}

// Round 5
// 40.946 us; speedup vs baseline: 1.4248x; 1.0010x over previous
//
#include <hip/hip_runtime.h>

#define NUM_IDS 64
#define NB 65                 // bins 0..64 (0 = background)
#define HIST_BINS (NB * NB)   // 4225
#define G1 128                // hist blocks
#define T1 256                // hist threads/block
#define BINS_PER_BLK 64
#define G2 ((HIST_BINS + BINS_PER_BLK - 1) / BINS_PER_BLK)  // 67
#define T2 256

// Kernel A: per-block LDS histogram -> private partial slice (no global atomics).
__global__ __launch_bounds__(T1) void isl_hist_kernel(
    const int* __restrict__ pred, const int* __restrict__ tru,
    int* __restrict__ part, int* __restrict__ counter, int n4) {
    __shared__ int lh[HIST_BINS];
    const int tid = threadIdx.x;
    if (blockIdx.x == 0 && tid == 0) *counter = 0;  // visible to B at dispatch boundary
    for (int i = tid; i < HIST_BINS; i += T1) lh[i] = 0;
    __syncthreads();

    const int4* __restrict__ p4 = (const int4*)pred;
    const int4* __restrict__ t4 = (const int4*)tru;
    const int stride = G1 * T1;
    int i = blockIdx.x * T1 + tid;
    int rounds = (n4 - i + stride - 1) / stride;

    // 4-deep hoisted loads for MLP; 1024x1024 gives exactly 8 rounds/thread.
    while (rounds >= 4) {
        int4 pa = p4[i];            int4 ta = t4[i];
        int4 pb = p4[i + stride];   int4 tb = t4[i + stride];
        int4 pc = p4[i + 2*stride]; int4 tc = t4[i + 2*stride];
        int4 pd = p4[i + 3*stride]; int4 td = t4[i + 3*stride];
        atomicAdd(&lh[pa.x * NB + ta.x], 1);
        atomicAdd(&lh[pa.y * NB + ta.y], 1);
        atomicAdd(&lh[pa.z * NB + ta.z], 1);
        atomicAdd(&lh[pa.w * NB + ta.w], 1);
        atomicAdd(&lh[pb.x * NB + tb.x], 1);
        atomicAdd(&lh[pb.y * NB + tb.y], 1);
        atomicAdd(&lh[pb.z * NB + tb.z], 1);
        atomicAdd(&lh[pb.w * NB + tb.w], 1);
        atomicAdd(&lh[pc.x * NB + tc.x], 1);
        atomicAdd(&lh[pc.y * NB + tc.y], 1);
        atomicAdd(&lh[pc.z * NB + tc.z], 1);
        atomicAdd(&lh[pc.w * NB + tc.w], 1);
        atomicAdd(&lh[pd.x * NB + td.x], 1);
        atomicAdd(&lh[pd.y * NB + td.y], 1);
        atomicAdd(&lh[pd.z * NB + td.z], 1);
        atomicAdd(&lh[pd.w * NB + td.w], 1);
        i += 4 * stride;
        rounds -= 4;
    }
    for (; rounds > 0; --rounds, i += stride) {
        int4 p = p4[i];
        int4 t = t4[i];
        atomicAdd(&lh[p.x * NB + t.x], 1);
        atomicAdd(&lh[p.y * NB + t.y], 1);
        atomicAdd(&lh[p.z * NB + t.z], 1);
        atomicAdd(&lh[p.w * NB + t.w], 1);
    }
    __syncthreads();

    int* dst = part + (size_t)blockIdx.x * HIST_BINS;
    for (int j = tid; j < HIST_BINS; j += T1) dst[j] = lh[j];
}

// Kernel B: parallel merge of partials -> C; last finished block computes loss.
__global__ __launch_bounds__(T2) void isl_reduce_kernel(
    const int* __restrict__ part, int* __restrict__ C,
    int* __restrict__ counter, float* __restrict__ out) {
    __shared__ int acc[4][BINS_PER_BLK];
    __shared__ int lh[HIST_BINS];
    __shared__ float ap[NUM_IDS], at[NUM_IDS];
    __shared__ float rowmax[NUM_IDS], colmax[NUM_IDS];
    __shared__ int is_last;

    const int tid = threadIdx.x;
    const int lane = tid & 63;
    const int wave = tid >> 6;          // 0..3
    const int bin = blockIdx.x * BINS_PER_BLK + lane;

    int s = 0;
    if (bin < HIST_BINS) {
#pragma unroll 8
        for (int r = wave; r < G1; r += 4)      // lanes -> consecutive bins: coalesced
            s += part[(size_t)r * HIST_BINS + bin];
    }
    acc[wave][lane] = s;
    __syncthreads();

    if (wave == 0 && bin < HIST_BINS)
        C[bin] = acc[0][lane] + acc[1][lane] + acc[2][lane] + acc[3][lane];

    __threadfence();
    if (tid == 0) {
        int old = atomicAdd(counter, 1);
        is_last = (old == G2 - 1);
    }
    __syncthreads();
    if (!is_last) return;

    // Coherent-point reads of the completed histogram (cross-XCD safe).
    for (int b = tid; b < HIST_BINS; b += T2) lh[b] = atomicAdd(&C[b], 0);
    __syncthreads();

    if (tid < NUM_IDS) {
        int s1 = 0;
        for (int j = 0; j < NB; ++j) s1 += lh[(tid + 1) * NB + j];
        ap[tid] = (float)s1;
        int s2 = 0;
        for (int k = 0; k < NB; ++k) s2 += lh[k * NB + (tid + 1)];
        at[tid] = (float)s2;
    }
    __syncthreads();

    if (tid < NUM_IDS) {
        float a = ap[tid];
        float m = 0.f;
        for (int j = 0; j < NUM_IDS; ++j) {
            float inter = (float)lh[(tid + 1) * NB + (j + 1)];
            float uni = a + at[j] - inter;
            float iou = (uni > 0.f) ? inter / uni : 0.f;
            m = fmaxf(m, iou);
        }
        rowmax[tid] = m;

        float b = at[tid];
        float m2 = 0.f;
        for (int k = 0; k < NUM_IDS; ++k) {
            float inter = (float)lh[(k + 1) * NB + (tid + 1)];
            float uni = ap[k] + b - inter;
            float iou = (uni > 0.f) ? inter / uni : 0.f;
            m2 = fmaxf(m2, iou);
        }
        colmax[tid] = m2;
    }
    __syncthreads();

    if (tid == 0) {
        float loss = 0.f, cnt = 0.f;
        for (int k = 0; k < NUM_IDS; ++k) {
            if (ap[k] > 0.f) { loss += 1.f - rowmax[k]; cnt += 1.f; }
            if (at[k] > 0.f) { loss += 1.f - colmax[k]; cnt += 1.f; }
        }
        out[0] = (cnt > 0.f) ? loss / cnt : 0.f;
    }
}

extern "C" void kernel_launch(void* const* d_in, const int* in_sizes, int n_in,
                              void* d_out, int out_size, void* d_ws, size_t ws_size,
                              hipStream_t stream) {
    const int* pred = (const int*)d_in[0];
    const int* tru  = (const int*)d_in[1];
    float* out = (float*)d_out;
    int n = in_sizes[0];  // 1024*1024

    int* part = (int*)d_ws;                       // [G1][4225] = 2.2 MB (ws is 256 MiB)
    int* C = part + (size_t)G1 * HIST_BINS;       // [4225]
    int* counter = C + HIST_BINS;                 // [1]

    isl_hist_kernel<<<G1, T1, 0, stream>>>(pred, tru, part, counter, n >> 2);
    isl_reduce_kernel<<<G2, T2, 0, stream>>>(part, C, counter, out);
}

// Round 6
// 38.456 us; speedup vs baseline: 1.5170x; 1.0647x over previous
//
#include <hip/hip_runtime.h>

#define NUM_IDS 64
#define NB 65              // bins 0..64 (0 = background)
#define HIST_BINS (NB * NB)   // 4225
#define PADBINS 4228          // padded to multiple of 4 for int4
#define GROUPS (PADBINS / 4)  // 1057
#define HB 32                 // histogram blocks
#define HT 512                // histogram threads/block

// Kernel 1: per-block joint histogram C[p][t], written to private slice of ws.
__global__ __launch_bounds__(HT) void isl_hist_kernel(
    const int* __restrict__ pred, const int* __restrict__ tru,
    int* __restrict__ part, int n4) {
    __shared__ int lh[PADBINS];
    for (int i = threadIdx.x; i < PADBINS; i += HT) lh[i] = 0;
    __syncthreads();

    const int4* __restrict__ p4 = (const int4*)pred;
    const int4* __restrict__ t4 = (const int4*)tru;
    int idx = blockIdx.x * HT + threadIdx.x;
    const int stride = HB * HT;
    int nfull = n4 / stride;
    int i = idx;
#pragma unroll 4
    for (int k = 0; k < nfull; ++k, i += stride) {
        int4 p = p4[i];
        int4 t = t4[i];
        atomicAdd(&lh[p.x * NB + t.x], 1);
        atomicAdd(&lh[p.y * NB + t.y], 1);
        atomicAdd(&lh[p.z * NB + t.z], 1);
        atomicAdd(&lh[p.w * NB + t.w], 1);
    }
    if (i < n4) {  // tail (absent for 1024x1024 but keep general)
        int4 p = p4[i];
        int4 t = t4[i];
        atomicAdd(&lh[p.x * NB + t.x], 1);
        atomicAdd(&lh[p.y * NB + t.y], 1);
        atomicAdd(&lh[p.z * NB + t.z], 1);
        atomicAdd(&lh[p.w * NB + t.w], 1);
    }
    __syncthreads();

    int base = blockIdx.x * PADBINS;
    for (int j = threadIdx.x; j < PADBINS; j += HT) part[base + j] = lh[j];
}

// Kernel 2: sum partials -> C, then areas, IoU maxes, final loss (one block).
__global__ __launch_bounds__(1024) void isl_reduce_kernel(
    const int* __restrict__ part, float* __restrict__ out) {
    __shared__ alignas(16) int C[PADBINS];
    __shared__ float ap[NUM_IDS], at[NUM_IDS];
    __shared__ float rowmax[NUM_IDS], colmax[NUM_IDS];

    int t = threadIdx.x;
    for (int g = t; g < GROUPS; g += 1024) {
        int4 s = make_int4(0, 0, 0, 0);
#pragma unroll 8
        for (int b = 0; b < HB; ++b) {
            const int4 v = *(const int4*)(part + b * PADBINS + (g << 2));
            s.x += v.x; s.y += v.y; s.z += v.z; s.w += v.w;
        }
        *(int4*)(&C[g << 2]) = s;
    }
    __syncthreads();

    if (t < NUM_IDS) {
        int s = 0;
        for (int j = 0; j < NB; ++j) s += C[(t + 1) * NB + j];
        ap[t] = (float)s;
        int s2 = 0;
        for (int i = 0; i < NB; ++i) s2 += C[i * NB + (t + 1)];
        at[t] = (float)s2;
    }
    __syncthreads();

    if (t < NUM_IDS) {
        float a = ap[t];
        float m = 0.f;
        for (int j = 0; j < NUM_IDS; ++j) {
            float inter = (float)C[(t + 1) * NB + (j + 1)];
            float uni = a + at[j] - inter;
            float iou = (uni > 0.f) ? inter / uni : 0.f;
            m = fmaxf(m, iou);
        }
        rowmax[t] = m;

        float b = at[t];
        float m2 = 0.f;
        for (int i = 0; i < NUM_IDS; ++i) {
            float inter = (float)C[(i + 1) * NB + (t + 1)];
            float uni = ap[i] + b - inter;
            float iou = (uni > 0.f) ? inter / uni : 0.f;
            m2 = fmaxf(m2, iou);
        }
        colmax[t] = m2;
    }
    __syncthreads();

    if (t == 0) {
        float loss = 0.f, cnt = 0.f;
        for (int i = 0; i < NUM_IDS; ++i) {
            if (ap[i] > 0.f) { loss += 1.f - rowmax[i]; cnt += 1.f; }
            if (at[i] > 0.f) { loss += 1.f - colmax[i]; cnt += 1.f; }
        }
        out[0] = (cnt > 0.f) ? loss / cnt : 0.f;
    }
}

extern "C" void kernel_launch(void* const* d_in, const int* in_sizes, int n_in,
                              void* d_out, int out_size, void* d_ws, size_t ws_size,
                              hipStream_t stream) {
    const int* pred = (const int*)d_in[0];
    const int* tru  = (const int*)d_in[1];
    float* out = (float*)d_out;
    int n = in_sizes[0];            // 1024*1024
    int* part = (int*)d_ws;         // HB * PADBINS ints = 541 KB

    isl_hist_kernel<<<HB, HT, 0, stream>>>(pred, tru, part, n >> 2);
    isl_reduce_kernel<<<1, 1024, 0, stream>>>(part, out);
}